// Round 3
// baseline (1460.388 us; speedup 1.0000x reference)
//
#include <hip/hip_runtime.h>
#include <math.h>

// Problem constants
#define Hdim 768
#define NH 12
#define HD 64
#define MM 16
#define KK 4
#define Bb 4
#define Nn 2048
#define NMB 128               // Nn/MM
#define EPSV 1e-5f
#define PLD 2320              // padded width of P / Wcat (2316 cols used)
#define NCOLS 2316            // 768*3 + 12

// ---------------------------------------------------------------------------
// Static device scratch (module-load allocated; avoids any d_ws overflow).
// ---------------------------------------------------------------------------
__device__ float g_tab[1024];
__device__ float g_Wcat[(size_t)Hdim * PLD + 512];      // +guard: B-tile over-read
__device__ float g_P[(size_t)Bb * Nn * PLD + 512];
__device__ float g_XQ[(size_t)Bb * NH * Nn * HD];       // reused as ubuf after scan
__device__ float g_XK[(size_t)Bb * NH * Nn * HD];
__device__ float g_XV[(size_t)Bb * NH * Nn * HD];
__device__ float g_lrv[(size_t)Bb * NH * Nn];
__device__ float g_y[(size_t)Bb * Nn * Hdim];

// ---------------------------------------------------------------------------
// Kernel 0: pack Wcat = [wq | wv | wg | lr_w^T] and build RoPE cos/sin table
// ---------------------------------------------------------------------------
__global__ __launch_bounds__(256) void prep_kernel(
    const float* __restrict__ wq, const float* __restrict__ wv,
    const float* __restrict__ wg, const float* __restrict__ lrw,
    float* __restrict__ Wcat, float* __restrict__ tab)
{
    int idx0 = blockIdx.x * 256 + threadIdx.x;
    if (idx0 < 512) {  // 16 pos x 32 freqs
        int pos = idx0 >> 5, k = idx0 & 31;
        double f = pow(10000.0, -(double)k / 32.0);
        double a = (double)pos * f;
        tab[2 * idx0 + 0] = (float)cos(a);
        tab[2 * idx0 + 1] = (float)sin(a);
    }
    const int total = Hdim * PLD;
    for (int i = idx0; i < total; i += 2048 * 256) {
        int k = i / PLD, j = i - k * PLD;
        float v;
        if (j < 768)       v = wq[k * 768 + j];
        else if (j < 1536) v = wv[k * 768 + (j - 768)];
        else if (j < 2304) v = wg[k * 768 + (j - 1536)];
        else if (j < NCOLS) v = lrw[(j - 2304) * 768 + k];
        else v = 0.f;
        Wcat[i] = v;
    }
}

// ---------------------------------------------------------------------------
// Tiled fp32 GEMM: C[M,N] = A[M,K] * B[K,N]  (row-major, ld in elements)
// 128x128 block tile, 256 threads, 8x8 per thread (split 4+4 for banks)
// ---------------------------------------------------------------------------
__global__ __launch_bounds__(256) void gemm_tiled(
    const float* __restrict__ A, int lda,
    const float* __restrict__ Bm, int ldb,
    float* __restrict__ C, int ldc,
    int M, int N, int K)
{
    __shared__ float As[16][132];
    __shared__ float Bs[16][132];
    const int tid = threadIdx.x;
    const int tx = tid & 15, ty = tid >> 4;
    const int row0 = blockIdx.y * 128;
    const int col0 = blockIdx.x * 128;
    const int r_lo = ty * 4, c_lo = tx * 4;

    float acc[8][8];
#pragma unroll
    for (int i = 0; i < 8; ++i)
#pragma unroll
        for (int j = 0; j < 8; ++j) acc[i][j] = 0.f;

    for (int kt = 0; kt < K; kt += 16) {
        // A tile: 128 rows x 16 k
#pragma unroll
        for (int i = 0; i < 2; ++i) {
            int id = tid + i * 256;
            int r = id >> 2, kq = (id & 3) * 4;
            const float4 a = *reinterpret_cast<const float4*>(
                &A[(size_t)(row0 + r) * lda + kt + kq]);
            As[kq + 0][r] = a.x; As[kq + 1][r] = a.y;
            As[kq + 2][r] = a.z; As[kq + 3][r] = a.w;
        }
        // B tile: 16 k x 128 cols (loads may over-read past N into guard pad;
        // the corresponding acc columns are discarded by the store mask)
#pragma unroll
        for (int i = 0; i < 2; ++i) {
            int id = tid + i * 256;
            int kr = id >> 5, jq = (id & 31) * 4;
            const float4 bv = *reinterpret_cast<const float4*>(
                &Bm[(size_t)(kt + kr) * ldb + col0 + jq]);
            *reinterpret_cast<float4*>(&Bs[kr][jq]) = bv;
        }
        __syncthreads();
#pragma unroll
        for (int k = 0; k < 16; ++k) {
            float a[8], bb[8];
            *reinterpret_cast<float4*>(&a[0]) = *reinterpret_cast<float4*>(&As[k][r_lo]);
            *reinterpret_cast<float4*>(&a[4]) = *reinterpret_cast<float4*>(&As[k][64 + r_lo]);
            *reinterpret_cast<float4*>(&bb[0]) = *reinterpret_cast<float4*>(&Bs[k][c_lo]);
            *reinterpret_cast<float4*>(&bb[4]) = *reinterpret_cast<float4*>(&Bs[k][64 + c_lo]);
#pragma unroll
            for (int i = 0; i < 8; ++i)
#pragma unroll
                for (int j = 0; j < 8; ++j)
                    acc[i][j] = fmaf(a[i], bb[j], acc[i][j]);
        }
        __syncthreads();
    }
#pragma unroll
    for (int i = 0; i < 8; ++i) {
        int rr = row0 + ((i < 4) ? (r_lo + i) : (64 + r_lo + i - 4));
        if (rr >= M) continue;
#pragma unroll
        for (int jb = 0; jb < 2; ++jb) {
            int cc = col0 + jb * 64 + c_lo;
            if (cc + 3 < N) {
                *reinterpret_cast<float4*>(&C[(size_t)rr * ldc + cc]) =
                    make_float4(acc[i][jb * 4 + 0], acc[i][jb * 4 + 1],
                                acc[i][jb * 4 + 2], acc[i][jb * 4 + 3]);
            } else {
#pragma unroll
                for (int jj = 0; jj < 4; ++jj)
                    if (cc + jj < N) C[(size_t)rr * ldc + cc + jj] = acc[i][jb * 4 + jj];
            }
        }
    }
}

// ---------------------------------------------------------------------------
// Kernel 2: causal conv (taps at offsets -4..-1) + RoPE + pack + lr sigmoid.
// One block per token.
// ---------------------------------------------------------------------------
__global__ __launch_bounds__(256) void conv_rope_kernel(
    const float* __restrict__ P, const int* __restrict__ pid,
    const float* __restrict__ cqk, const float* __restrict__ cqb,
    const float* __restrict__ ckk, const float* __restrict__ ckb,
    const float* __restrict__ lr_b, const float* __restrict__ tab,
    float* __restrict__ XQp, float* __restrict__ XKp, float* __restrict__ XVp,
    float* __restrict__ lrv)
{
    const int t = blockIdx.x;            // global token
    const int b = t >> 11, n = t & 2047;
    const int tid = threadIdx.x;
    __shared__ float xq_s[768], xk_s[768];
    const size_t rowP = (size_t)t * PLD;

#pragma unroll
    for (int i = 0; i < 3; ++i) {
        int c = tid + i * 256;
        float aq = cqb[c], ak = ckb[c];
#pragma unroll
        for (int w = 0; w < 4; ++w) {
            int np = n + w - 4;
            if (np >= 0) {
                float x = P[(size_t)(t + w - 4) * PLD + c];
                aq = fmaf(cqk[w * 768 + c], x, aq);
                ak = fmaf(ckk[w * 768 + c], x, ak);
            }
        }
        xq_s[c] = aq; xk_s[c] = ak;
        int h = c >> 6, d = c & 63;
        XVp[((size_t)(b * NH + h)) * (Nn * HD) + n * 64 + d] = P[rowP + 768 + c];
    }
    if (tid < NH) {
        float x = P[rowP + 2304 + tid] + lr_b[tid];
        lrv[((size_t)(b * NH + tid)) * Nn + n] = 1.f / (1.f + expf(-x));
    }
    __syncthreads();
    const int pos = pid[t] & 15;
    for (int p = tid; p < 384; p += 256) {
        int h = p >> 5, k = p & 31;
        float cv = tab[(pos * 32 + k) * 2 + 0];
        float sv = tab[(pos * 32 + k) * 2 + 1];
        int c0 = h * 64 + 2 * k;
        size_t base = ((size_t)(b * NH + h)) * (Nn * HD) + n * 64 + 2 * k;
        float x0 = xq_s[c0], x1 = xq_s[c0 + 1];
        XQp[base + 0] = x0 * cv - x1 * sv;
        XQp[base + 1] = x0 * sv + x1 * cv;
        x0 = xk_s[c0]; x1 = xk_s[c0 + 1];
        XKp[base + 0] = x0 * cv - x1 * sv;
        XKp[base + 1] = x0 * sv + x1 * cv;
    }
}

// ---------------------------------------------------------------------------
// Kernel 3: TTT scan.  One block per (b,h); 256 threads; 128 sequential steps.
// W1 (64x64) in registers: thread (q=tid>>6, e=tid&63) owns rows 16q..16q+15
// of column e.
// ---------------------------------------------------------------------------
__global__ __launch_bounds__(256) void ttt_scan_kernel(
    const float* __restrict__ XQp, const float* __restrict__ XKp,
    const float* __restrict__ XVp, const float* __restrict__ lrv,
    const float* __restrict__ W1g, const float* __restrict__ b1g,
    const float* __restrict__ gam, const float* __restrict__ bet,
    const float* __restrict__ tokidx, float* __restrict__ ybuf)
{
    const int h = blockIdx.x, b = blockIdx.y;
    const int bh = b * NH + h;
    const int tid = threadIdx.x;
    const int e = tid & 63, q = tid >> 6;
    const int q16 = q * 16;

    __shared__ float xq_s[16][68], xk_s[16][68], xv_s[16][68], grad_s[16][68];
    __shared__ float part[2][4][16][64];
    __shared__ float b1_s[64], g_s[64], bt_s[64];
    __shared__ float lrs_s[16], tokv_s[16], alpha_s[16];
    __shared__ float coef_s[16][17];

    float W1own[16];
#pragma unroll
    for (int r = 0; r < 16; ++r)
        W1own[r] = W1g[h * 4096 + (q16 + r) * 64 + e];
    if (tid < 64) {
        b1_s[tid] = b1g[h * 64 + tid];
        g_s[tid]  = gam[h * 64 + tid];
        bt_s[tid] = bet[h * 64 + tid];
    }
    if (tid < 16)
        tokv_s[tid] = fmaxf(tokidx[tid] + 1.f / (float)(tid + 1), 0.f);

    const size_t base = (size_t)bh * (Nn * HD);
    const int m_st = tid >> 4, d_st = (tid & 15) * 4;

    auto red16 = [](float x) {
        x += __shfl_xor(x, 1); x += __shfl_xor(x, 2);
        x += __shfl_xor(x, 4); x += __shfl_xor(x, 8);
        return x;
    };

    float zb[4];

    for (int c = 0; c < NMB; ++c) {
        // ---- stage tiles ----
        {
            size_t off = base + (size_t)c * 1024 + tid * 4;
            *reinterpret_cast<float4*>(&xq_s[m_st][d_st]) =
                *reinterpret_cast<const float4*>(XQp + off);
            *reinterpret_cast<float4*>(&xk_s[m_st][d_st]) =
                *reinterpret_cast<const float4*>(XKp + off);
            *reinterpret_cast<float4*>(&xv_s[m_st][d_st]) =
                *reinterpret_cast<const float4*>(XVp + off);
            if (tid < 16) lrs_s[tid] = lrv[(size_t)bh * Nn + c * 16 + tid];
        }
        __syncthreads();

        // ---- phase 1: partial products xk@W1, xq@W1 ----
        float pz[16], pq[16];
#pragma unroll
        for (int m = 0; m < 16; ++m) {
            float xkv[16], xqv[16];
            *reinterpret_cast<float4*>(&xkv[0])  = *reinterpret_cast<float4*>(&xk_s[m][q16 + 0]);
            *reinterpret_cast<float4*>(&xkv[4])  = *reinterpret_cast<float4*>(&xk_s[m][q16 + 4]);
            *reinterpret_cast<float4*>(&xkv[8])  = *reinterpret_cast<float4*>(&xk_s[m][q16 + 8]);
            *reinterpret_cast<float4*>(&xkv[12]) = *reinterpret_cast<float4*>(&xk_s[m][q16 + 12]);
            *reinterpret_cast<float4*>(&xqv[0])  = *reinterpret_cast<float4*>(&xq_s[m][q16 + 0]);
            *reinterpret_cast<float4*>(&xqv[4])  = *reinterpret_cast<float4*>(&xq_s[m][q16 + 4]);
            *reinterpret_cast<float4*>(&xqv[8])  = *reinterpret_cast<float4*>(&xq_s[m][q16 + 8]);
            *reinterpret_cast<float4*>(&xqv[12]) = *reinterpret_cast<float4*>(&xq_s[m][q16 + 12]);
            float az = 0.f, aq = 0.f;
#pragma unroll
            for (int r = 0; r < 16; ++r) {
                az = fmaf(xkv[r], W1own[r], az);
                aq = fmaf(xqv[r], W1own[r], aq);
            }
            pz[m] = az; pq[m] = aq;
        }
#pragma unroll
        for (int m = 0; m < 16; ++m) {
            part[0][q][m][e] = pz[m];
            part[1][q][m][e] = pq[m];
        }
        __syncthreads();

        // ---- phase 2: reduce Z1, LN-L2 backward -> grad ----
        {
            const int m = tid >> 4, e0 = (tid & 15) * 4;
            float z1[4];
#pragma unroll
            for (int jj = 0; jj < 4; ++jj) {
                int ee = e0 + jj;
                z1[jj] = b1_s[ee] + part[0][0][m][ee] + part[0][1][m][ee]
                                  + part[0][2][m][ee] + part[0][3][m][ee];
                zb[jj] = part[1][0][m][ee] + part[1][1][m][ee]
                       + part[1][2][m][ee] + part[1][3][m][ee];
            }
            float lsum = z1[0] + z1[1] + z1[2] + z1[3];
            lsum = red16(lsum);
            const float mu = lsum * (1.f / 64.f);
            float lss = 0.f;
#pragma unroll
            for (int jj = 0; jj < 4; ++jj) { float d = z1[jj] - mu; lss += d * d; }
            lss = red16(lss);
            const float rstd = 1.f / sqrtf(lss * (1.f / 64.f) + EPSV);
            float gy[4], xh[4], sgy = 0.f, sgx = 0.f;
#pragma unroll
            for (int jj = 0; jj < 4; ++jj) {
                int ee = e0 + jj;
                xh[jj] = (z1[jj] - mu) * rstd;
                float tgt = xv_s[m][ee] - xk_s[m][ee];
                gy[jj] = (g_s[ee] * xh[jj] + bt_s[ee] - tgt) * g_s[ee];
                sgy += gy[jj]; sgx += gy[jj] * xh[jj];
            }
            sgy = red16(sgy); sgx = red16(sgx);
            const float sc = rstd * (1.f / 64.f);
#pragma unroll
            for (int jj = 0; jj < 4; ++jj)
                grad_s[m][e0 + jj] = (64.f * gy[jj] - sgy - xh[jj] * sgx) * sc;
        }
        __syncthreads();

        // ---- phase 3: attn + coefficients ----
        {
            const int i3 = tid >> 4, j3 = tid & 15;
            float cf = 0.f;
            if (j3 <= i3) {
                float s = 0.f;
#pragma unroll
                for (int d = 0; d < 64; d += 4) {
                    float4 a = *reinterpret_cast<float4*>(&xq_s[i3][d]);
                    float4 bq = *reinterpret_cast<float4*>(&xk_s[j3][d]);
                    s += a.x * bq.x + a.y * bq.y + a.z * bq.z + a.w * bq.w;
                }
                cf = tokv_s[i3] * lrs_s[j3] * (1.f / 64.f) * (1.f + s);
            }
            coef_s[i3][j3] = cf;
            if (tid < 16) alpha_s[tid] = tokv_s[15] * lrs_s[tid] * (1.f / 64.f);
        }
        __syncthreads();

        // ---- phase 4: Z1_bar, output LN, write y ----
        {
            const int m = tid >> 4, e0 = (tid & 15) * 4;
            float zf[4];
#pragma unroll
            for (int jj = 0; jj < 4; ++jj) zf[jj] = zb[jj] + b1_s[e0 + jj];
            for (int j = 0; j <= m; ++j) {
                float cfv = coef_s[m][j];
                float4 g4 = *reinterpret_cast<float4*>(&grad_s[j][e0]);
                zf[0] = fmaf(-cfv, g4.x, zf[0]);
                zf[1] = fmaf(-cfv, g4.y, zf[1]);
                zf[2] = fmaf(-cfv, g4.z, zf[2]);
                zf[3] = fmaf(-cfv, g4.w, zf[3]);
            }
            float lsum = zf[0] + zf[1] + zf[2] + zf[3];
            lsum = red16(lsum);
            const float mu = lsum * (1.f / 64.f);
            float lss = 0.f;
#pragma unroll
            for (int jj = 0; jj < 4; ++jj) { float d = zf[jj] - mu; lss += d * d; }
            lss = red16(lss);
            const float rstd = 1.f / sqrtf(lss * (1.f / 64.f) + EPSV);
            float ov[4];
#pragma unroll
            for (int jj = 0; jj < 4; ++jj) {
                int ee = e0 + jj;
                ov[jj] = xq_s[m][ee] + ((zf[jj] - mu) * rstd * g_s[ee] + bt_s[ee]);
            }
            size_t yoff = (size_t)(b * Nn + c * 16 + m) * 768 + h * 64 + e0;
            *reinterpret_cast<float4*>(&ybuf[yoff]) =
                make_float4(ov[0], ov[1], ov[2], ov[3]);
        }
        // phase 5 writes b1_s which phase 4 reads; barrier required.
        __syncthreads();

        // ---- phase 5: W1 / b1 update ----
        {
#pragma unroll
            for (int m = 0; m < 16; ++m) {
                float f = alpha_s[m] * grad_s[m][e];
                float xkv[16];
                *reinterpret_cast<float4*>(&xkv[0])  = *reinterpret_cast<float4*>(&xk_s[m][q16 + 0]);
                *reinterpret_cast<float4*>(&xkv[4])  = *reinterpret_cast<float4*>(&xk_s[m][q16 + 4]);
                *reinterpret_cast<float4*>(&xkv[8])  = *reinterpret_cast<float4*>(&xk_s[m][q16 + 8]);
                *reinterpret_cast<float4*>(&xkv[12]) = *reinterpret_cast<float4*>(&xk_s[m][q16 + 12]);
#pragma unroll
                for (int r = 0; r < 16; ++r)
                    W1own[r] = fmaf(-f, xkv[r], W1own[r]);
            }
            if (q == 0) {
                float sb = 0.f;
#pragma unroll
                for (int m = 0; m < 16; ++m)
                    sb += alpha_s[m] * grad_s[m][e];
                b1_s[e] -= sb;
            }
        }
        __syncthreads();
    }
}

// ---------------------------------------------------------------------------
// Kernel 4a: post layernorm + gelu gate -> u.  One block per token.
// ---------------------------------------------------------------------------
__global__ __launch_bounds__(256) void post_gate_kernel(
    const float* __restrict__ ybuf, const float* __restrict__ P,
    const float* __restrict__ ps, const float* __restrict__ pb,
    float* __restrict__ u)
{
    const int t = blockIdx.x;
    const int tid = threadIdx.x;
    __shared__ float red_a[4], red_b[4];
    float v[3];
    float lsum = 0.f;
#pragma unroll
    for (int i = 0; i < 3; ++i) {
        int c = tid + i * 256;
        v[i] = ybuf[(size_t)t * 768 + c];
        lsum += v[i];
    }
#pragma unroll
    for (int m = 1; m < 64; m <<= 1) lsum += __shfl_xor(lsum, m);
    if ((tid & 63) == 0) red_a[tid >> 6] = lsum;
    __syncthreads();
    const float mu = (red_a[0] + red_a[1] + red_a[2] + red_a[3]) * (1.f / 768.f);
    float lv = 0.f;
#pragma unroll
    for (int i = 0; i < 3; ++i) { float d = v[i] - mu; lv += d * d; }
#pragma unroll
    for (int m = 1; m < 64; m <<= 1) lv += __shfl_xor(lv, m);
    if ((tid & 63) == 0) red_b[tid >> 6] = lv;
    __syncthreads();
    const float var = (red_b[0] + red_b[1] + red_b[2] + red_b[3]) * (1.f / 768.f);
    const float rstd = 1.f / sqrtf(var + EPSV);
#pragma unroll
    for (int i = 0; i < 3; ++i) {
        int c = tid + i * 256;
        float g = P[(size_t)t * PLD + 1536 + c];
        float gl = 0.5f * g * (1.f + tanhf(0.7978845608028654f * (g + 0.044715f * g * g * g)));
        u[(size_t)t * 768 + c] = gl * ((v[i] - mu) * rstd * ps[c] + pb[c]);
    }
}

// ---------------------------------------------------------------------------
// Launcher — scratch comes from static device globals, NOT d_ws.
// ---------------------------------------------------------------------------
extern "C" void kernel_launch(void* const* d_in, const int* in_sizes, int n_in,
                              void* d_out, int out_size, void* d_ws, size_t ws_size,
                              hipStream_t stream)
{
    const float* hs   = (const float*)d_in[0];
    const int*   pid  = (const int*)  d_in[1];
    const float* wq   = (const float*)d_in[2];
    const float* wv   = (const float*)d_in[3];
    const float* wo   = (const float*)d_in[4];
    const float* wg   = (const float*)d_in[5];
    const float* cqk  = (const float*)d_in[6];
    const float* cqb  = (const float*)d_in[7];
    const float* ckk  = (const float*)d_in[8];
    const float* ckb  = (const float*)d_in[9];
    const float* lrw  = (const float*)d_in[10];
    const float* lrb  = (const float*)d_in[11];
    const float* lti  = (const float*)d_in[12];
    const float* gam  = (const float*)d_in[13];
    const float* bet  = (const float*)d_in[14];
    const float* ps   = (const float*)d_in[15];
    const float* pb   = (const float*)d_in[16];
    const float* W1g  = (const float*)d_in[17];
    const float* b1g  = (const float*)d_in[18];
    float* out = (float*)d_out;
    (void)d_ws; (void)ws_size; (void)in_sizes; (void)n_in; (void)out_size;

    float *tab = nullptr, *Wcat = nullptr, *P = nullptr, *XQp = nullptr,
          *XKp = nullptr, *XVp = nullptr, *lrv = nullptr, *ybuf = nullptr;
    hipGetSymbolAddress((void**)&tab,  HIP_SYMBOL(g_tab));
    hipGetSymbolAddress((void**)&Wcat, HIP_SYMBOL(g_Wcat));
    hipGetSymbolAddress((void**)&P,    HIP_SYMBOL(g_P));
    hipGetSymbolAddress((void**)&XQp,  HIP_SYMBOL(g_XQ));
    hipGetSymbolAddress((void**)&XKp,  HIP_SYMBOL(g_XK));
    hipGetSymbolAddress((void**)&XVp,  HIP_SYMBOL(g_XV));
    hipGetSymbolAddress((void**)&lrv,  HIP_SYMBOL(g_lrv));
    hipGetSymbolAddress((void**)&ybuf, HIP_SYMBOL(g_y));
    float* ubuf = XQp;   // XQp dead after scan

    hipLaunchKernelGGL(prep_kernel, dim3(2048), dim3(256), 0, stream,
                       wq, wv, wg, lrw, Wcat, tab);
    hipLaunchKernelGGL(gemm_tiled, dim3(19, 64), dim3(256), 0, stream,
                       hs, Hdim, Wcat, PLD, P, PLD, Bb * Nn, NCOLS, Hdim);
    hipLaunchKernelGGL(conv_rope_kernel, dim3(Bb * Nn), dim3(256), 0, stream,
                       P, pid, cqk, cqb, ckk, ckb, lrb, tab, XQp, XKp, XVp, lrv);
    hipLaunchKernelGGL(ttt_scan_kernel, dim3(NH, Bb), dim3(256), 0, stream,
                       XQp, XKp, XVp, lrv, W1g, b1g, gam, bet, lti, ybuf);
    hipLaunchKernelGGL(post_gate_kernel, dim3(Bb * Nn), dim3(256), 0, stream,
                       ybuf, P, ps, pb, ubuf);
    hipLaunchKernelGGL(gemm_tiled, dim3(6, 64), dim3(256), 0, stream,
                       ubuf, Hdim, wo, Hdim, out, Hdim, Bb * Nn, Hdim, Hdim);
}

// Round 5
// 1261.843 us; speedup vs baseline: 1.1573x; 1.1573x over previous
//
#include <hip/hip_runtime.h>
#include <math.h>

// Problem constants
#define Hdim 768
#define NH 12
#define HD 64
#define MM 16
#define KK 4
#define Bb 4
#define Nn 2048
#define NMB 128               // Nn/MM
#define EPSV 1e-5f
#define PLD 2320              // padded width of P / Wcat (2316 cols used)
#define NCOLS 2316            // 768*3 + 12

// ---------------------------------------------------------------------------
// Static device scratch (module-load allocated; avoids any d_ws overflow).
// ---------------------------------------------------------------------------
__device__ float g_tab[1024];
__device__ float g_Wcat[(size_t)Hdim * PLD + 512];      // +guard: B-tile over-read
__device__ float g_P[(size_t)Bb * Nn * PLD + 512];
__device__ float g_XQ[(size_t)Bb * NH * Nn * HD];       // reused as ubuf after scan
__device__ float g_XK[(size_t)Bb * NH * Nn * HD];
__device__ float g_XV[(size_t)Bb * NH * Nn * HD];
__device__ float g_lrv[(size_t)Bb * NH * Nn];
__device__ float g_y[(size_t)Bb * Nn * Hdim];

// ---------------------------------------------------------------------------
// DPP-based 16-lane sum (bit-exact equivalent of shfl_xor 1,2,4,8 tree).
// ---------------------------------------------------------------------------
template <int CTRL>
__device__ __forceinline__ float dpp_mov(float x) {
    return __int_as_float(__builtin_amdgcn_update_dpp(
        0, __float_as_int(x), CTRL, 0xF, 0xF, true));
}
__device__ __forceinline__ float red16_dpp(float x) {
    x += dpp_mov<0xB1>(x);    // quad_perm [1,0,3,2]  == xor 1
    x += dpp_mov<0x4E>(x);    // quad_perm [2,3,0,1]  == xor 2
    x += dpp_mov<0x141>(x);   // row_half_mirror      == quad ^ 1 (quad-uniform by now)
    x += dpp_mov<0x140>(x);   // row_mirror           == quad-pair ^ 1
    return x;
}

// ---------------------------------------------------------------------------
// Kernel 0: pack Wcat = [wq | wv | wg | lr_w^T] and build RoPE cos/sin table
// ---------------------------------------------------------------------------
__global__ __launch_bounds__(256) void prep_kernel(
    const float* __restrict__ wq, const float* __restrict__ wv,
    const float* __restrict__ wg, const float* __restrict__ lrw,
    float* __restrict__ Wcat, float* __restrict__ tab)
{
    int idx0 = blockIdx.x * 256 + threadIdx.x;
    if (idx0 < 512) {  // 16 pos x 32 freqs
        int pos = idx0 >> 5, k = idx0 & 31;
        double f = pow(10000.0, -(double)k / 32.0);
        double a = (double)pos * f;
        tab[2 * idx0 + 0] = (float)cos(a);
        tab[2 * idx0 + 1] = (float)sin(a);
    }
    const int total = Hdim * PLD;
    for (int i = idx0; i < total; i += 2048 * 256) {
        int k = i / PLD, j = i - k * PLD;
        float v;
        if (j < 768)       v = wq[k * 768 + j];
        else if (j < 1536) v = wv[k * 768 + (j - 768)];
        else if (j < 2304) v = wg[k * 768 + (j - 1536)];
        else if (j < NCOLS) v = lrw[(j - 2304) * 768 + k];
        else v = 0.f;
        Wcat[i] = v;
    }
}

// ---------------------------------------------------------------------------
// Tiled fp32 GEMM: C[M,N] = A[M,K] * B[K,N]  (row-major, ld in elements)
// ---------------------------------------------------------------------------
__global__ __launch_bounds__(256) void gemm_tiled(
    const float* __restrict__ A, int lda,
    const float* __restrict__ Bm, int ldb,
    float* __restrict__ C, int ldc,
    int M, int N, int K)
{
    __shared__ float As[16][132];
    __shared__ float Bs[16][132];
    const int tid = threadIdx.x;
    const int tx = tid & 15, ty = tid >> 4;
    const int row0 = blockIdx.y * 128;
    const int col0 = blockIdx.x * 128;
    const int r_lo = ty * 4, c_lo = tx * 4;

    float acc[8][8];
#pragma unroll
    for (int i = 0; i < 8; ++i)
#pragma unroll
        for (int j = 0; j < 8; ++j) acc[i][j] = 0.f;

    for (int kt = 0; kt < K; kt += 16) {
#pragma unroll
        for (int i = 0; i < 2; ++i) {
            int id = tid + i * 256;
            int r = id >> 2, kq = (id & 3) * 4;
            const float4 a = *reinterpret_cast<const float4*>(
                &A[(size_t)(row0 + r) * lda + kt + kq]);
            As[kq + 0][r] = a.x; As[kq + 1][r] = a.y;
            As[kq + 2][r] = a.z; As[kq + 3][r] = a.w;
        }
#pragma unroll
        for (int i = 0; i < 2; ++i) {
            int id = tid + i * 256;
            int kr = id >> 5, jq = (id & 31) * 4;
            const float4 bv = *reinterpret_cast<const float4*>(
                &Bm[(size_t)(kt + kr) * ldb + col0 + jq]);
            *reinterpret_cast<float4*>(&Bs[kr][jq]) = bv;
        }
        __syncthreads();
#pragma unroll
        for (int k = 0; k < 16; ++k) {
            float a[8], bb[8];
            *reinterpret_cast<float4*>(&a[0]) = *reinterpret_cast<float4*>(&As[k][r_lo]);
            *reinterpret_cast<float4*>(&a[4]) = *reinterpret_cast<float4*>(&As[k][64 + r_lo]);
            *reinterpret_cast<float4*>(&bb[0]) = *reinterpret_cast<float4*>(&Bs[k][c_lo]);
            *reinterpret_cast<float4*>(&bb[4]) = *reinterpret_cast<float4*>(&Bs[k][64 + c_lo]);
#pragma unroll
            for (int i = 0; i < 8; ++i)
#pragma unroll
                for (int j = 0; j < 8; ++j)
                    acc[i][j] = fmaf(a[i], bb[j], acc[i][j]);
        }
        __syncthreads();
    }
#pragma unroll
    for (int i = 0; i < 8; ++i) {
        int rr = row0 + ((i < 4) ? (r_lo + i) : (64 + r_lo + i - 4));
        if (rr >= M) continue;
#pragma unroll
        for (int jb = 0; jb < 2; ++jb) {
            int cc = col0 + jb * 64 + c_lo;
            if (cc + 3 < N) {
                *reinterpret_cast<float4*>(&C[(size_t)rr * ldc + cc]) =
                    make_float4(acc[i][jb * 4 + 0], acc[i][jb * 4 + 1],
                                acc[i][jb * 4 + 2], acc[i][jb * 4 + 3]);
            } else {
#pragma unroll
                for (int jj = 0; jj < 4; ++jj)
                    if (cc + jj < N) C[(size_t)rr * ldc + cc + jj] = acc[i][jb * 4 + jj];
            }
        }
    }
}

// ---------------------------------------------------------------------------
// Kernel 2: causal conv + RoPE + pack + lr sigmoid.  One block per token.
// ---------------------------------------------------------------------------
__global__ __launch_bounds__(256) void conv_rope_kernel(
    const float* __restrict__ P, const int* __restrict__ pid,
    const float* __restrict__ cqk, const float* __restrict__ cqb,
    const float* __restrict__ ckk, const float* __restrict__ ckb,
    const float* __restrict__ lr_b, const float* __restrict__ tab,
    float* __restrict__ XQp, float* __restrict__ XKp, float* __restrict__ XVp,
    float* __restrict__ lrv)
{
    const int t = blockIdx.x;
    const int b = t >> 11, n = t & 2047;
    const int tid = threadIdx.x;
    __shared__ float xq_s[768], xk_s[768];
    const size_t rowP = (size_t)t * PLD;

#pragma unroll
    for (int i = 0; i < 3; ++i) {
        int c = tid + i * 256;
        float aq = cqb[c], ak = ckb[c];
#pragma unroll
        for (int w = 0; w < 4; ++w) {
            int np = n + w - 4;
            if (np >= 0) {
                float x = P[(size_t)(t + w - 4) * PLD + c];
                aq = fmaf(cqk[w * 768 + c], x, aq);
                ak = fmaf(ckk[w * 768 + c], x, ak);
            }
        }
        xq_s[c] = aq; xk_s[c] = ak;
        int h = c >> 6, d = c & 63;
        XVp[((size_t)(b * NH + h)) * (Nn * HD) + n * 64 + d] = P[rowP + 768 + c];
    }
    if (tid < NH) {
        float x = P[rowP + 2304 + tid] + lr_b[tid];
        lrv[((size_t)(b * NH + tid)) * Nn + n] = 1.f / (1.f + expf(-x));
    }
    __syncthreads();
    const int pos = pid[t] & 15;
    for (int p = tid; p < 384; p += 256) {
        int h = p >> 5, k = p & 31;
        float cv = tab[(pos * 32 + k) * 2 + 0];
        float sv = tab[(pos * 32 + k) * 2 + 1];
        int c0 = h * 64 + 2 * k;
        size_t base = ((size_t)(b * NH + h)) * (Nn * HD) + n * 64 + 2 * k;
        float x0 = xq_s[c0], x1 = xq_s[c0 + 1];
        XQp[base + 0] = x0 * cv - x1 * sv;
        XQp[base + 1] = x0 * sv + x1 * cv;
        x0 = xk_s[c0]; x1 = xk_s[c0 + 1];
        XKp[base + 0] = x0 * cv - x1 * sv;
        XKp[base + 1] = x0 * sv + x1 * cv;
    }
}

// ---------------------------------------------------------------------------
// Kernel 3: TTT scan — pipelined 3-barrier version.
// One block per (b,h); 256 threads; 128 sequential chunks.
// W1 in registers: thread (q=tid>>6, e=tid&63) owns rows 16q..16q+15, col e.
// Double-buffered x-tiles + b1; chunk c+1 prefetched to regs during P1 of c.
//   P1: issue prefetch(c+1); part = xk@W1, xq@W1          | barrier
//   P2: z1/zb; grad (DPP LN-bwd); coef; alpha; stage(c+1) | barrier
//   P3: Z1_bar + out-LN + y store; W1 update; b1[nxt]     | barrier
// ---------------------------------------------------------------------------
__global__ __launch_bounds__(256) void ttt_scan_kernel(
    const float* __restrict__ XQp, const float* __restrict__ XKp,
    const float* __restrict__ XVp, const float* __restrict__ lrv,
    const float* __restrict__ W1g, const float* __restrict__ b1g,
    const float* __restrict__ gam, const float* __restrict__ bet,
    const float* __restrict__ tokidx, float* __restrict__ ybuf)
{
    const int h = blockIdx.x, b = blockIdx.y;
    const int bh = b * NH + h;
    const int tid = threadIdx.x;
    const int e = tid & 63, q = tid >> 6;
    const int q16 = q * 16;

    __shared__ float xq_s[2][16][68], xk_s[2][16][68], xv_s[2][16][68];
    __shared__ float grad_s[16][68];
    __shared__ float part[2][4][16][64];
    __shared__ float b1_s[2][64], g_s[64], bt_s[64];
    __shared__ float lrs_s[2][16], tokv_s[16], alpha_s[16];
    __shared__ float coef_s[16][17];

    float W1own[16];
#pragma unroll
    for (int r = 0; r < 16; ++r)
        W1own[r] = W1g[h * 4096 + (q16 + r) * 64 + e];
    if (tid < 64) {
        b1_s[0][tid] = b1g[h * 64 + tid];
        g_s[tid]  = gam[h * 64 + tid];
        bt_s[tid] = bet[h * 64 + tid];
    }
    if (tid < 16)
        tokv_s[tid] = fmaxf(tokidx[tid] + 1.f / (float)(tid + 1), 0.f);

    const size_t base = (size_t)bh * (Nn * HD);
    const int m_st = tid >> 4, d_st = (tid & 15) * 4;

    // ---- preload chunk 0 and stage it ----
    float4 pfq, pfk, pfv;
    float pflr = 0.f;
    {
        size_t off = base + (size_t)tid * 4;
        pfq = *reinterpret_cast<const float4*>(XQp + off);
        pfk = *reinterpret_cast<const float4*>(XKp + off);
        pfv = *reinterpret_cast<const float4*>(XVp + off);
        if (tid < 16) pflr = lrv[(size_t)bh * Nn + tid];
    }
    *reinterpret_cast<float4*>(&xq_s[0][m_st][d_st]) = pfq;
    *reinterpret_cast<float4*>(&xk_s[0][m_st][d_st]) = pfk;
    *reinterpret_cast<float4*>(&xv_s[0][m_st][d_st]) = pfv;
    if (tid < 16) lrs_s[0][tid] = pflr;
    __syncthreads();

    float zb[4];
    int cur = 0;

    for (int c = 0; c < NMB; ++c) {
        const int nxt = cur ^ 1;

        // ---- P1: issue prefetch for c+1; compute partial products ----
        {
            const int cn = (c < NMB - 1) ? (c + 1) : c;
            size_t off = base + (size_t)cn * 1024 + tid * 4;
            pfq = *reinterpret_cast<const float4*>(XQp + off);
            pfk = *reinterpret_cast<const float4*>(XKp + off);
            pfv = *reinterpret_cast<const float4*>(XVp + off);
            if (tid < 16) pflr = lrv[(size_t)bh * Nn + cn * 16 + tid];
        }
#pragma unroll
        for (int m = 0; m < 16; ++m) {
            float xkv[16], xqv[16];
            *reinterpret_cast<float4*>(&xkv[0])  = *reinterpret_cast<float4*>(&xk_s[cur][m][q16 + 0]);
            *reinterpret_cast<float4*>(&xkv[4])  = *reinterpret_cast<float4*>(&xk_s[cur][m][q16 + 4]);
            *reinterpret_cast<float4*>(&xkv[8])  = *reinterpret_cast<float4*>(&xk_s[cur][m][q16 + 8]);
            *reinterpret_cast<float4*>(&xkv[12]) = *reinterpret_cast<float4*>(&xk_s[cur][m][q16 + 12]);
            *reinterpret_cast<float4*>(&xqv[0])  = *reinterpret_cast<float4*>(&xq_s[cur][m][q16 + 0]);
            *reinterpret_cast<float4*>(&xqv[4])  = *reinterpret_cast<float4*>(&xq_s[cur][m][q16 + 4]);
            *reinterpret_cast<float4*>(&xqv[8])  = *reinterpret_cast<float4*>(&xq_s[cur][m][q16 + 8]);
            *reinterpret_cast<float4*>(&xqv[12]) = *reinterpret_cast<float4*>(&xq_s[cur][m][q16 + 12]);
            float az = 0.f, aq = 0.f;
#pragma unroll
            for (int r = 0; r < 16; ++r) {
                az = fmaf(xkv[r], W1own[r], az);
                aq = fmaf(xqv[r], W1own[r], aq);
            }
            part[0][q][m][e] = az;
            part[1][q][m][e] = aq;
        }
        __syncthreads();

        // ---- P2: grad + coef + alpha + stage(c+1) ----
        {
            *reinterpret_cast<float4*>(&xq_s[nxt][m_st][d_st]) = pfq;
            *reinterpret_cast<float4*>(&xk_s[nxt][m_st][d_st]) = pfk;
            *reinterpret_cast<float4*>(&xv_s[nxt][m_st][d_st]) = pfv;
            if (tid < 16) lrs_s[nxt][tid] = pflr;

            const int m = tid >> 4, e0 = (tid & 15) * 4;
            float4 p0 = *reinterpret_cast<float4*>(&part[0][0][m][e0]);
            float4 p1 = *reinterpret_cast<float4*>(&part[0][1][m][e0]);
            float4 p2 = *reinterpret_cast<float4*>(&part[0][2][m][e0]);
            float4 p3 = *reinterpret_cast<float4*>(&part[0][3][m][e0]);
            float4 q0 = *reinterpret_cast<float4*>(&part[1][0][m][e0]);
            float4 q1 = *reinterpret_cast<float4*>(&part[1][1][m][e0]);
            float4 q2 = *reinterpret_cast<float4*>(&part[1][2][m][e0]);
            float4 q3 = *reinterpret_cast<float4*>(&part[1][3][m][e0]);
            float z1[4];
            z1[0] = b1_s[cur][e0 + 0] + p0.x + p1.x + p2.x + p3.x;
            z1[1] = b1_s[cur][e0 + 1] + p0.y + p1.y + p2.y + p3.y;
            z1[2] = b1_s[cur][e0 + 2] + p0.z + p1.z + p2.z + p3.z;
            z1[3] = b1_s[cur][e0 + 3] + p0.w + p1.w + p2.w + p3.w;
            zb[0] = q0.x + q1.x + q2.x + q3.x;
            zb[1] = q0.y + q1.y + q2.y + q3.y;
            zb[2] = q0.z + q1.z + q2.z + q3.z;
            zb[3] = q0.w + q1.w + q2.w + q3.w;

            float lsum = red16_dpp(z1[0] + z1[1] + z1[2] + z1[3]);
            const float mu = lsum * (1.f / 64.f);
            float lss = 0.f;
#pragma unroll
            for (int jj = 0; jj < 4; ++jj) { float d = z1[jj] - mu; lss += d * d; }
            lss = red16_dpp(lss);
            const float rstd = 1.f / sqrtf(lss * (1.f / 64.f) + EPSV);
            float gy[4], xh[4], sgy = 0.f, sgx = 0.f;
#pragma unroll
            for (int jj = 0; jj < 4; ++jj) {
                int ee = e0 + jj;
                xh[jj] = (z1[jj] - mu) * rstd;
                float tgt = xv_s[cur][m][ee] - xk_s[cur][m][ee];
                gy[jj] = (g_s[ee] * xh[jj] + bt_s[ee] - tgt) * g_s[ee];
                sgy += gy[jj]; sgx += gy[jj] * xh[jj];
            }
            sgy = red16_dpp(sgy); sgx = red16_dpp(sgx);
            const float sc = rstd * (1.f / 64.f);
#pragma unroll
            for (int jj = 0; jj < 4; ++jj)
                grad_s[m][e0 + jj] = (64.f * gy[jj] - sgy - xh[jj] * sgx) * sc;

            const int i3 = m, j3 = (tid & 15);
            float cf = 0.f;
            if (j3 <= i3) {
                float s = 0.f;
#pragma unroll
                for (int d = 0; d < 64; d += 4) {
                    float4 a  = *reinterpret_cast<float4*>(&xq_s[cur][i3][d]);
                    float4 bq = *reinterpret_cast<float4*>(&xk_s[cur][j3][d]);
                    s += a.x * bq.x + a.y * bq.y + a.z * bq.z + a.w * bq.w;
                }
                cf = tokv_s[i3] * lrs_s[cur][j3] * (1.f / 64.f) * (1.f + s);
            }
            coef_s[i3][j3] = cf;
            if (tid < 16) alpha_s[tid] = tokv_s[15] * lrs_s[cur][tid] * (1.f / 64.f);
        }
        __syncthreads();

        // ---- P3: Z1_bar + out-LN + y; W1/b1 update ----
        {
            const int m = tid >> 4, e0 = (tid & 15) * 4;
            float zf[4];
#pragma unroll
            for (int jj = 0; jj < 4; ++jj) zf[jj] = zb[jj] + b1_s[cur][e0 + jj];
            for (int j = 0; j <= m; ++j) {
                float cfv = coef_s[m][j];
                float4 g4 = *reinterpret_cast<float4*>(&grad_s[j][e0]);
                zf[0] = fmaf(-cfv, g4.x, zf[0]);
                zf[1] = fmaf(-cfv, g4.y, zf[1]);
                zf[2] = fmaf(-cfv, g4.z, zf[2]);
                zf[3] = fmaf(-cfv, g4.w, zf[3]);
            }
            float lsum = red16_dpp(zf[0] + zf[1] + zf[2] + zf[3]);
            const float mu = lsum * (1.f / 64.f);
            float lss = 0.f;
#pragma unroll
            for (int jj = 0; jj < 4; ++jj) { float d = zf[jj] - mu; lss += d * d; }
            lss = red16_dpp(lss);
            const float rstd = 1.f / sqrtf(lss * (1.f / 64.f) + EPSV);
            float ov[4];
#pragma unroll
            for (int jj = 0; jj < 4; ++jj) {
                int ee = e0 + jj;
                ov[jj] = xq_s[cur][m][ee] + ((zf[jj] - mu) * rstd * g_s[ee] + bt_s[ee]);
            }
            size_t yoff = (size_t)(b * Nn + c * 16 + m) * 768 + h * 64 + e0;
            *reinterpret_cast<float4*>(&ybuf[yoff]) =
                make_float4(ov[0], ov[1], ov[2], ov[3]);
        }
        {
#pragma unroll
            for (int m = 0; m < 16; ++m) {
                float f = alpha_s[m] * grad_s[m][e];
                float xkv[16];
                *reinterpret_cast<float4*>(&xkv[0])  = *reinterpret_cast<float4*>(&xk_s[cur][m][q16 + 0]);
                *reinterpret_cast<float4*>(&xkv[4])  = *reinterpret_cast<float4*>(&xk_s[cur][m][q16 + 4]);
                *reinterpret_cast<float4*>(&xkv[8])  = *reinterpret_cast<float4*>(&xk_s[cur][m][q16 + 8]);
                *reinterpret_cast<float4*>(&xkv[12]) = *reinterpret_cast<float4*>(&xk_s[cur][m][q16 + 12]);
#pragma unroll
                for (int r = 0; r < 16; ++r)
                    W1own[r] = fmaf(-f, xkv[r], W1own[r]);
            }
            if (q == 0) {
                float sb = 0.f;
#pragma unroll
                for (int m = 0; m < 16; ++m)
                    sb += alpha_s[m] * grad_s[m][e];
                b1_s[nxt][e] = b1_s[cur][e] - sb;
            }
        }
        __syncthreads();
        cur = nxt;
    }
}

// ---------------------------------------------------------------------------
// Kernel 4a: post layernorm + gelu gate -> u.  One block per token.
// ---------------------------------------------------------------------------
__global__ __launch_bounds__(256) void post_gate_kernel(
    const float* __restrict__ ybuf, const float* __restrict__ P,
    const float* __restrict__ ps, const float* __restrict__ pb,
    float* __restrict__ u)
{
    const int t = blockIdx.x;
    const int tid = threadIdx.x;
    __shared__ float red_a[4], red_b[4];
    float v[3];
    float lsum = 0.f;
#pragma unroll
    for (int i = 0; i < 3; ++i) {
        int c = tid + i * 256;
        v[i] = ybuf[(size_t)t * 768 + c];
        lsum += v[i];
    }
#pragma unroll
    for (int m = 1; m < 64; m <<= 1) lsum += __shfl_xor(lsum, m);
    if ((tid & 63) == 0) red_a[tid >> 6] = lsum;
    __syncthreads();
    const float mu = (red_a[0] + red_a[1] + red_a[2] + red_a[3]) * (1.f / 768.f);
    float lv = 0.f;
#pragma unroll
    for (int i = 0; i < 3; ++i) { float d = v[i] - mu; lv += d * d; }
#pragma unroll
    for (int m = 1; m < 64; m <<= 1) lv += __shfl_xor(lv, m);
    if ((tid & 63) == 0) red_b[tid >> 6] = lv;
    __syncthreads();
    const float var = (red_b[0] + red_b[1] + red_b[2] + red_b[3]) * (1.f / 768.f);
    const float rstd = 1.f / sqrtf(var + EPSV);
#pragma unroll
    for (int i = 0; i < 3; ++i) {
        int c = tid + i * 256;
        float g = P[(size_t)t * PLD + 1536 + c];
        float gl = 0.5f * g * (1.f + tanhf(0.7978845608028654f * (g + 0.044715f * g * g * g)));
        u[(size_t)t * 768 + c] = gl * ((v[i] - mu) * rstd * ps[c] + pb[c]);
    }
}

// ---------------------------------------------------------------------------
// Launcher — scratch comes from static device globals, NOT d_ws.
// ---------------------------------------------------------------------------
extern "C" void kernel_launch(void* const* d_in, const int* in_sizes, int n_in,
                              void* d_out, int out_size, void* d_ws, size_t ws_size,
                              hipStream_t stream)
{
    const float* hs   = (const float*)d_in[0];
    const int*   pid  = (const int*)  d_in[1];
    const float* wq   = (const float*)d_in[2];
    const float* wv   = (const float*)d_in[3];
    const float* wo   = (const float*)d_in[4];
    const float* wg   = (const float*)d_in[5];
    const float* cqk  = (const float*)d_in[6];
    const float* cqb  = (const float*)d_in[7];
    const float* ckk  = (const float*)d_in[8];
    const float* ckb  = (const float*)d_in[9];
    const float* lrw  = (const float*)d_in[10];
    const float* lrb  = (const float*)d_in[11];
    const float* lti  = (const float*)d_in[12];
    const float* gam  = (const float*)d_in[13];
    const float* bet  = (const float*)d_in[14];
    const float* ps   = (const float*)d_in[15];
    const float* pb   = (const float*)d_in[16];
    const float* W1g  = (const float*)d_in[17];
    const float* b1g  = (const float*)d_in[18];
    float* out = (float*)d_out;
    (void)d_ws; (void)ws_size; (void)in_sizes; (void)n_in; (void)out_size;

    float *tab = nullptr, *Wcat = nullptr, *P = nullptr, *XQp = nullptr,
          *XKp = nullptr, *XVp = nullptr, *lrv = nullptr, *ybuf = nullptr;
    hipGetSymbolAddress((void**)&tab,  HIP_SYMBOL(g_tab));
    hipGetSymbolAddress((void**)&Wcat, HIP_SYMBOL(g_Wcat));
    hipGetSymbolAddress((void**)&P,    HIP_SYMBOL(g_P));
    hipGetSymbolAddress((void**)&XQp,  HIP_SYMBOL(g_XQ));
    hipGetSymbolAddress((void**)&XKp,  HIP_SYMBOL(g_XK));
    hipGetSymbolAddress((void**)&XVp,  HIP_SYMBOL(g_XV));
    hipGetSymbolAddress((void**)&lrv,  HIP_SYMBOL(g_lrv));
    hipGetSymbolAddress((void**)&ybuf, HIP_SYMBOL(g_y));
    float* ubuf = XQp;   // XQp dead after scan

    hipLaunchKernelGGL(prep_kernel, dim3(2048), dim3(256), 0, stream,
                       wq, wv, wg, lrw, Wcat, tab);
    hipLaunchKernelGGL(gemm_tiled, dim3(19, 64), dim3(256), 0, stream,
                       hs, Hdim, Wcat, PLD, P, PLD, Bb * Nn, NCOLS, Hdim);
    hipLaunchKernelGGL(conv_rope_kernel, dim3(Bb * Nn), dim3(256), 0, stream,
                       P, pid, cqk, cqb, ckk, ckb, lrb, tab, XQp, XKp, XVp, lrv);
    hipLaunchKernelGGL(ttt_scan_kernel, dim3(NH, Bb), dim3(256), 0, stream,
                       XQp, XKp, XVp, lrv, W1g, b1g, gam, bet, lti, ybuf);
    hipLaunchKernelGGL(post_gate_kernel, dim3(Bb * Nn), dim3(256), 0, stream,
                       ybuf, P, ps, pb, ubuf);
    hipLaunchKernelGGL(gemm_tiled, dim3(6, 64), dim3(256), 0, stream,
                       ubuf, Hdim, wo, Hdim, out, Hdim, Bb * Nn, Hdim, Hdim);
}